// Round 4
// baseline (267.272 us; speedup 1.0000x reference)
//
#include <hip/hip_runtime.h>

#define BB 16
#define HH 512
#define WW 512
#define HWP (HH*WW)
#define NMAP (BB*HWP)

// ---------------------------------------------------------------------------
// One guided-filter stage, fully fused: box1(s,q) -> pointwise A,b ->
// box1(A,b) -> emit. Vertical running column-sums for both box passes;
// horizontal sums via LDS row exchanges. Pass-1 needs colsums over
// [w0-2P, w0+256+2P) (edge threads carry 2P halo cols/side); pass-2 needs
// A,b over [w0-P, w0+256+P) (P halo cols/side). A,b history kept in an LDS
// ring (2P+2 slots, pow2) so the leaving row can be subtracted.
// STAGE 1: input x -> s,q on the fly; emits mA1,mb1 and updated s',q'.
// STAGE 2: input s,q; emits mA2,mb2 and updated s'',q''.
// STAGE 3: input s,q; emit folds mA1..mb2 + x + w1 into the final output.
// ---------------------------------------------------------------------------
template <int PAD, int CH, int STAGE>
__global__ __launch_bounds__(256) void stagek(
    const float* __restrict__ p0, const float* __restrict__ p1,
    const float* __restrict__ p2, const float* __restrict__ p3,
    const float* __restrict__ p4, const float* __restrict__ p5,
    const float* __restrict__ px, const float* __restrict__ w1,
    float* __restrict__ o0, float* __restrict__ o1,
    float* __restrict__ o2, float* __restrict__ o3, float eps)
{
    constexpr int XW = 256 + 4 * PAD;               // pass-1 colsum space
    constexpr int AW = 256 + 2 * PAD;               // A-column space
    constexpr int RING = (2 * PAD + 2 <= 4) ? 4 : ((2 * PAD + 2 <= 8) ? 8 : 16);
    constexpr int NCH = HH / CH;
    __shared__ float ex1[2][XW];
    __shared__ float ex2[2][AW];
    __shared__ float ring[RING][2][AW];
    __shared__ float wsh[27];

    int bx = blockIdx.x;
    int chunk = bx % NCH;
    int strip = (bx / NCH) & 1;
    int b = bx / (NCH * 2);
    int t = threadIdx.x;
    int w0 = strip * 256;
    int w = w0 + t;
    int h0 = chunk * CH;
    size_t mb_ = (size_t)b * HWP;                   // 1-channel map base
    size_t xb_ = (size_t)b * 3 * HWP;               // 3-channel base (x / out)

    if (STAGE == 3 && t < 27) wsh[t] = w1[t];

    // pass-1 halo: 2P columns per side
    bool lh1 = (t < 2 * PAD), rh1 = (t >= 256 - 2 * PAD);
    int  h1col = lh1 ? (w0 - 2 * PAD + t) : (w + 2 * PAD);
    int  h1idx = lh1 ? t : (t + 4 * PAD);
    bool h1 = lh1 || rh1;
    bool h1v = h1 && ((unsigned)h1col < (unsigned)WW);
    // pass-2 halo: P columns per side
    bool lh2 = (t < PAD), rh2 = (t >= 256 - PAD);
    int  a2col = lh2 ? (w0 - PAD + t) : (w + PAD);
    int  a2idx = lh2 ? t : (t + 2 * PAD);
    bool h2 = lh2 || rh2;
    bool h2v = h2 && ((unsigned)a2col < (unsigned)WW);

    auto ldsq = [&](int r, int c, float& sv, float& qv) {
        if constexpr (STAGE == 1) {
            size_t ii = xb_ + (size_t)r * WW + c;
            float a0 = px[ii], a1 = px[ii + HWP], a2 = px[ii + 2 * HWP];
            sv = a0 + a1 + a2;
            qv = a0 * a0 + a1 * a1 + a2 * a2;
        } else {
            size_t ii = mb_ + (size_t)r * WW + c;
            sv = p0[ii]; qv = p1[ii];
        }
    };

    // prime pass-1 colsums with rows [h0-2P, h0-1]
    float cs0 = 0.f, cs1 = 0.f, hc0 = 0.f, hc1 = 0.f;
    for (int rr = h0 - 2 * PAD; rr < h0; ++rr) {
        if ((unsigned)rr < (unsigned)HH) {
            float sv, qv;
            ldsq(rr, w, sv, qv); cs0 += sv; cs1 += qv;
            if (h1v) { ldsq(rr, h1col, sv, qv); hc0 += sv; hc1 += qv; }
        }
    }
    float csA = 0.f, csB = 0.f, csAH = 0.f, csBH = 0.f;

    for (int r = h0 - PAD; r < h0 + CH + PAD; ++r) {
        // enter row r+P into pass-1 colsums
        int re = r + PAD;
        if ((unsigned)re < (unsigned)HH) {
            float sv, qv;
            ldsq(re, w, sv, qv); cs0 += sv; cs1 += qv;
            if (h1v) { ldsq(re, h1col, sv, qv); hc0 += sv; hc1 += qv; }
        }
        ex1[0][t + 2 * PAD] = cs0; ex1[1][t + 2 * PAD] = cs1;
        if (h1) { ex1[0][h1idx] = h1v ? hc0 : 0.f; ex1[1][h1idx] = h1v ? hc1 : 0.f; }
        __syncthreads();

        // pointwise A,b at A-row r for owned A-columns
        bool rin = (unsigned)r < (unsigned)HH;
        int hlo = r - PAD < 0 ? 0 : r - PAD;
        int hhi = r + PAD > HH - 1 ? HH - 1 : r + PAD;
        float rowc = (float)(hhi - hlo + 1);
        float Am = 0.f, Bm = 0.f, Ah = 0.f, Bh = 0.f;
        if (rin) {
            float ss = 0.f, qq = 0.f;
#pragma unroll
            for (int d = 0; d <= 2 * PAD; ++d) {
                ss += ex1[0][t + PAD + d]; qq += ex1[1][t + PAD + d];
            }
            int wlo = w - PAD < 0 ? 0 : w - PAD;
            int whi = w + PAD > WW - 1 ? WW - 1 : w + PAD;
            float Nc = 3.f * rowc * (float)(whi - wlo + 1);
            float mean = ss / Nc;
            float var = qq / Nc - mean * mean;
            Am = var / (var + eps);
            Bm = mean * (1.f - Am);
            if (h2 && h2v) {
                float s2 = 0.f, q2 = 0.f;
#pragma unroll
                for (int d = 0; d <= 2 * PAD; ++d) {
                    s2 += ex1[0][a2idx + d]; q2 += ex1[1][a2idx + d];
                }
                int wlo2 = a2col - PAD < 0 ? 0 : a2col - PAD;
                int whi2 = a2col + PAD > WW - 1 ? WW - 1 : a2col + PAD;
                float Nc2 = 3.f * rowc * (float)(whi2 - wlo2 + 1);
                float mean2 = s2 / Nc2;
                float var2 = q2 / Nc2 - mean2 * mean2;
                Ah = var2 / (var2 + eps);
                Bh = mean2 * (1.f - Ah);
            }
        }
        // pass-2: push A-row into ring + running colsums
        int slot = (r + 1024) & (RING - 1);
        ring[slot][0][t + PAD] = Am; ring[slot][1][t + PAD] = Bm;
        csA += Am; csB += Bm;
        if (h2) { ring[slot][0][a2idx] = Ah; ring[slot][1][a2idx] = Bh; csAH += Ah; csBH += Bh; }

        int h = r - PAD;                            // candidate output row
        if (h >= h0) {                              // block-uniform
            ex2[0][t + PAD] = csA; ex2[1][t + PAD] = csB;
            if (h2) { ex2[0][a2idx] = csAH; ex2[1][a2idx] = csBH; }
            __syncthreads();
            float mAr = 0.f, mbr = 0.f;
#pragma unroll
            for (int d = 0; d <= 2 * PAD; ++d) {
                mAr += ex2[0][t + d]; mbr += ex2[1][t + d];
            }
            size_t oi = mb_ + (size_t)h * WW + w;
            if constexpr (STAGE == 3) {
                float a1 = 3.f * p2[oi], b1 = 3.f * p3[oi];
                float a2v = 3.f * p4[oi], b2v = 3.f * p5[oi];
                float a3 = 3.f * mAr, b3 = 3.f * mbr;
                float P1 = a1,        Q1 = b1;
                float P2 = a2v * P1,  Q2 = a2v * Q1 + b2v;
                float P3 = a3 * P2,   Q3 = a3 * Q2 + b3;
                float al[3] = {1.f - P1, P1 - P2, P2 - P3};
                float be[3] = {-Q1,      Q1 - Q2, Q2 - Q3};
                size_t xi = xb_ + (size_t)h * WW + w;
                float x0 = px[xi], x1 = px[xi + HWP], x2 = px[xi + 2 * HWP];
#pragma unroll
                for (int o = 0; o < 3; ++o) {
                    float acc = 0.f;
#pragma unroll
                    for (int g = 0; g < 3; ++g) {
                        float wa = wsh[o * 9 + g * 3 + 0];
                        float wb = wsh[o * 9 + g * 3 + 1];
                        float wc = wsh[o * 9 + g * 3 + 2];
                        acc += al[g] * (wa * x0 + wb * x1 + wc * x2)
                             + be[g] * (wa + wb + wc);
                    }
                    o0[xi + (size_t)o * HWP] = acc;
                }
            } else {
                o0[oi] = mAr; o1[oi] = mbr;
                float sv, qv;
                ldsq(h, w, sv, qv);                 // L1/L2 hit (touched 2P rows ago)
                float mA = 3.f * mAr, mbv = 3.f * mbr;
                o2[oi] = mA * sv + 3.f * mbv;
                o3[oi] = mA * mA * qv + 2.f * mA * mbv * sv + 3.f * mbv * mbv;
            }
            // A-row h-P leaves the pass-2 window
            int os = (r - 2 * PAD + 1024) & (RING - 1);
            csA -= ring[os][0][t + PAD]; csB -= ring[os][1][t + PAD];
            if (h2) { csAH -= ring[os][0][a2idx]; csBH -= ring[os][1][a2idx]; }
            __syncthreads();                        // ex1/ex2 reuse guard
        } else {
            __syncthreads();                        // uniform ex1 reuse guard
        }
        // leave row r-P from pass-1 colsums (reload: L1/L2 hit)
        int rl = r - PAD;
        if ((unsigned)rl < (unsigned)HH) {
            float sv, qv;
            ldsq(rl, w, sv, qv); cs0 -= sv; cs1 -= qv;
            if (h1v) { ldsq(rl, h1col, sv, qv); hc0 -= sv; hc1 -= qv; }
        }
    }
}

extern "C" void kernel_launch(void* const* d_in, const int* in_sizes, int n_in,
                              void* d_out, int out_size, void* d_ws, size_t ws_size,
                              hipStream_t stream) {
    (void)in_sizes; (void)n_in; (void)out_size; (void)ws_size;
    const float* x  = (const float*)d_in[0];
    const float* w1 = (const float*)d_in[1];
    float* out = (float*)d_out;
    float* ws = (float*)d_ws;

    // 8 maps of B*H*W floats = 134 MB workspace
    float* sA  = ws + 0ull * NMAP;
    float* qA  = ws + 1ull * NMAP;
    float* sB  = ws + 2ull * NMAP;
    float* qB  = ws + 3ull * NMAP;
    float* mA1 = ws + 4ull * NMAP;
    float* mb1 = ws + 5ull * NMAP;
    float* mA2 = ws + 6ull * NMAP;
    float* mb2 = ws + 7ull * NMAP;

    dim3 bl(256);

    // stage 1: k=3 (PAD=1), eps=0.16 — x -> mA1,mb1 + s',q'
    stagek<1, 16, 1><<<dim3(BB * 2 * (HH / 16)), bl, 0, stream>>>(
        nullptr, nullptr, nullptr, nullptr, nullptr, nullptr, x, w1,
        mA1, mb1, sA, qA, 0.16f);

    // stage 2: k=7 (PAD=3), eps=0.04 — s',q' -> mA2,mb2 + s'',q''
    stagek<3, 16, 2><<<dim3(BB * 2 * (HH / 16)), bl, 0, stream>>>(
        sA, qA, nullptr, nullptr, nullptr, nullptr, x, w1,
        mA2, mb2, sB, qB, 0.04f);

    // stage 3: k=15 (PAD=7), eps=0.01 — s'',q'' + mA1..mb2 + x -> out
    stagek<7, 32, 3><<<dim3(BB * 2 * (HH / 32)), bl, 0, stream>>>(
        sB, qB, mA1, mb1, mA2, mb2, x, w1,
        out, nullptr, nullptr, nullptr, 0.01f);
}